// Round 1
// baseline (1040.358 us; speedup 1.0000x reference)
//
#include <hip/hip_runtime.h>

#define B_ 1024
#define T_ 366
#define NS_ 365
#define CD_ 24
#define NTASK (B_ * NS_)

__device__ __forceinline__ float rdlane(float v, int k) {
    return __int_as_float(__builtin_amdgcn_readlane(__float_as_int(v), k));
}

__device__ __forceinline__ float sigm(float x) {
    return __fdividef(1.f, 1.f + __expf(-x));
}

// ---------------- Phase 1: sequential recurrence, one wave per batch element ----------------
__global__ __launch_bounds__(64, 1) void mclstm_phase1(
    const float* __restrict__ X, const float* __restrict__ ORY,
    const float* __restrict__ Wr, const float* __restrict__ br,
    const float* __restrict__ Wp, const float* __restrict__ bp,
    const float* __restrict__ Wc, const float* __restrict__ bc,
    const float* __restrict__ Wa, const float* __restrict__ ba,
    float* __restrict__ Ccell)
{
    const int b = blockIdx.x;
    const int l = threadIdx.x;
    __shared__ float zbuf[CD_ * 25];   // 24 rows, stride 25 (bank-conflict-free)
    __shared__ float pbuf[64];         // part(0..23) cons(24..47) assim(48)

    // redis weights for rows e = l + 64*j, masked columns {0..23, 25}
    float wrg[9][25], brg[9];
    int zaddr[9];
#pragma unroll
    for (int j = 0; j < 9; ++j) {
        const int e = l + 64 * j;
        const float* w = Wr + e * 29;
#pragma unroll
        for (int k = 0; k < 24; ++k) wrg[j][k] = w[k];
        wrg[j][24] = w[25];            // rad coefficient
        brg[j] = br[e];
        zaddr[j] = (e / 24) * 25 + (e % 24);
    }

    // one extra row per lane: part / cons / assim
    float wx[29];
    float bx = 0.f;
#pragma unroll
    for (int k = 0; k < 29; ++k) wx[k] = 0.f;
    if (l < 24) {
#pragma unroll
        for (int k = 0; k < 29; ++k) wx[k] = Wp[l * 29 + k];
        bx = bp[l];
    } else if (l < 48) {
#pragma unroll
        for (int k = 0; k < 29; ++k) wx[k] = Wc[(l - 24) * 29 + k];
        bx = bc[l - 24];
    } else if (l == 48) {
#pragma unroll
        for (int k = 0; k < 29; ++k) wx[k] = Wa[k];
        bx = ba[0];
    }

    float vC = 0.f;      // lane c < 24 holds C[c]
    float Ncum = 0.f;

    const float* xrow = X + (size_t)b * T_ * 4;
    const float* orow = ORY + (size_t)b * T_ * 7;
    float rad = xrow[0], tmx = xrow[1], tmn = xrow[2], x3 = xrow[3];
    float dvs = orow[0];

    for (int t = 0; t < NS_; ++t) {
        // software-prefetch next step's scalars
        const int tn = (t + 1 < NS_) ? t + 1 : t;
        const float nrad = xrow[tn * 4 + 0];
        const float ntmx = xrow[tn * 4 + 1];
        const float ntmn = xrow[tn * 4 + 2];
        const float nx3  = xrow[tn * 4 + 3];
        const float ndvs = orow[tn * 7];

        Ncum += x3;

        // broadcast C into wave-uniform (SGPR) values
        float Cs[24];
#pragma unroll
        for (int k = 0; k < 24; ++k) Cs[k] = rdlane(vC, k);

        // C_potential
        const float tave = 0.5f * (tmx + tmn);
        const float cl = fminf(fmaxf(tave * 50.f, 10.f), 40.f);
        const float eff = 0.54f - (cl - 10.f) * (0.18f / 30.f);
        const float cpot = rad * (eff * (2.f * 0.5f / 3.6f * (12.f / 44.f)));

        // all dot products (redis rows + one extra row)
#pragma unroll
        for (int j = 0; j < 9; ++j) {
            float z = brg[j];
#pragma unroll
            for (int k = 0; k < 24; ++k) z = fmaf(wrg[j][k], Cs[k], z);
            z = fmaf(wrg[j][24], rad, z);
            zbuf[zaddr[j]] = z;
        }
        {
            float z = bx;
#pragma unroll
            for (int k = 0; k < 24; ++k) z = fmaf(wx[k], Cs[k], z);
            z = fmaf(wx[24], dvs, z);
            z = fmaf(wx[25], rad, z);
            z = fmaf(wx[26], tmx, z);
            z = fmaf(wx[27], tmn, z);
            z = fmaf(wx[28], Ncum, z);
            pbuf[l] = z;
        }
        __syncthreads();

        // part softmax across lanes 0..23 (butterfly within 32-lane group)
        float pz = (l < 24) ? pbuf[l] : -1e30f;
        float pm = pz;
#pragma unroll
        for (int o = 1; o < 32; o <<= 1) pm = fmaxf(pm, __shfl_xor(pm, o));
        float pe = (l < 24) ? __expf(pz - pm) : 0.f;
        float ps = pe;
#pragma unroll
        for (int o = 1; o < 32; o <<= 1) ps += __shfl_xor(ps, o);
        const float part = __fdividef(pe, ps);

        const float cons  = sigm(pbuf[24 + ((l < 24) ? l : 0)]);
        const float assim = sigm(pbuf[48]);

        const float Cmid = (vC + assim * cpot * part) * (1.f - cons); // lane c<24

        // redis row softmax: lane r<24 owns row r; fold Cmid[r]/sum into the row
        const int r = (l < 24) ? l : 0;
        float zr[24];
#pragma unroll
        for (int c = 0; c < 24; ++c) zr[c] = zbuf[r * 25 + c];
        float m2 = zr[0];
#pragma unroll
        for (int c = 1; c < 24; ++c) m2 = fmaxf(m2, zr[c]);
        float ss = 0.f;
#pragma unroll
        for (int c = 0; c < 24; ++c) { zr[c] = __expf(zr[c] - m2); ss += zr[c]; }
        const float fac = __fdividef(Cmid, ss);
        __syncthreads();
        if (l < 24) {
#pragma unroll
            for (int c = 0; c < 24; ++c) zbuf[l * 25 + c] = zr[c] * fac;
        }
        __syncthreads();

        // einsum: Cnew[c] = sum_r Cmid[r] * P[r][c]  (column sums)
        const int cc = (l < 24) ? l : 0;
        float Cn = 0.f;
#pragma unroll
        for (int rr = 0; rr < 24; ++rr) Cn += zbuf[rr * 25 + cc];

        if (l < 24) Ccell[((size_t)b * NS_ + t) * CD_ + l] = Cn;
        vC = Cn;
        __syncthreads();

        rad = nrad; tmx = ntmx; tmn = ntmn; x3 = nx3; dvs = ndvs;
    }
}

// ---------------- Phase 2: C_conv + all_day, one (b,t) task per lane ----------------
__global__ __launch_bounds__(256) void mclstm_phase2(
    const float* __restrict__ X, const float* __restrict__ ORY,
    const float* __restrict__ Wr, const float* __restrict__ br,
    const float* __restrict__ c2a, const float* __restrict__ g2y,
    const float* __restrict__ Ccell, float* __restrict__ allday,
    float* __restrict__ Cconv)
{
    const int tid = blockIdx.x * 256 + threadIdx.x;

    // all_day[:,0,:] = ORY[:,0,:7]
    if (tid < B_) {
#pragma unroll
        for (int k = 0; k < 7; ++k)
            allday[(size_t)tid * T_ * 7 + k] = ORY[(size_t)tid * T_ * 7 + k];
    }
    if (tid >= NTASK) return;
    const int b = tid / NS_;
    const int t = tid - b * NS_;

    const float* Cp = Ccell + (size_t)tid * CD_;
    float C[24];
#pragma unroll
    for (int q = 0; q < 6; ++q) {
        const float4 v = *(const float4*)(Cp + 4 * q);
        C[4 * q + 0] = v.x; C[4 * q + 1] = v.y; C[4 * q + 2] = v.z; C[4 * q + 3] = v.w;
    }
    const float rad = X[((size_t)b * T_ + t) * 4];

    float Cc[24];
#pragma unroll
    for (int c = 0; c < 24; ++c) Cc[c] = 0.f;

    // 24 gate rows; weights are wave-uniform -> scalar loads; C[r] reloaded from
    // global (L1-hit) to keep all register indexing compile-time-constant.
    for (int r = 0; r < 24; ++r) {
        float z[24];
#pragma unroll
        for (int c = 0; c < 24; ++c) {
            const float* w = Wr + (r * 24 + c) * 29;
            float zz = fmaf(w[25], rad, br[r * 24 + c]);
#pragma unroll
            for (int k = 0; k < 24; ++k) zz = fmaf(w[k], C[k], zz);
            z[c] = zz;
        }
        float m = z[0];
#pragma unroll
        for (int c = 1; c < 24; ++c) m = fmaxf(m, z[c]);
        float ss = 0.f;
#pragma unroll
        for (int c = 0; c < 24; ++c) { z[c] = __expf(z[c] - m); ss += z[c]; }
        const float fac = __fdividef(Cp[r], ss);
#pragma unroll
        for (int c = 0; c < 24; ++c) Cc[c] = fmaf(z[c], fac, Cc[c]);
    }

    float* cv = Cconv + (size_t)tid * CD_;
#pragma unroll
    for (int q = 0; q < 6; ++q) {
        float4 v;
        v.x = Cc[4 * q + 0]; v.y = Cc[4 * q + 1]; v.z = Cc[4 * q + 2]; v.w = Cc[4 * q + 3];
        *(float4*)(cv + 4 * q) = v;
    }

    // all_day row t+1
    float pai = 0.f;
#pragma unroll
    for (int c = 0; c < 24; ++c) pai += fabsf(C[c] * c2a[c]);
    float lea = 0.f, ste = 0.f, gra = 0.f, yie = 0.f;
#pragma unroll
    for (int c = 0; c < 8; ++c) lea += C[c];
#pragma unroll
    for (int c = 8; c < 16; ++c) ste += C[c];
#pragma unroll
    for (int c = 16; c < 24; ++c) { gra += C[c]; yie += fabsf(C[c] * g2y[c - 16]); }
    lea /= 0.419f; ste /= 0.431f; gra /= 0.487f; yie /= 0.487f;
    const float agb = lea + ste + gra;

    float* ad = allday + ((size_t)b * T_ + (t + 1)) * 7;
    ad[0] = ORY[((size_t)b * T_ + (t + 1)) * 7];
    ad[1] = pai; ad[2] = lea; ad[3] = ste; ad[4] = gra; ad[5] = agb; ad[6] = yie;
}

extern "C" void kernel_launch(void* const* d_in, const int* in_sizes, int n_in,
                              void* d_out, int out_size, void* d_ws, size_t ws_size,
                              hipStream_t stream) {
    const float* X   = (const float*)d_in[0];
    const float* ORY = (const float*)d_in[1];
    const float* Wr  = (const float*)d_in[2];
    const float* br  = (const float*)d_in[3];
    const float* Wp  = (const float*)d_in[4];
    const float* bp  = (const float*)d_in[5];
    const float* Wc  = (const float*)d_in[6];
    const float* bc  = (const float*)d_in[7];
    const float* Wa  = (const float*)d_in[8];
    const float* ba  = (const float*)d_in[9];
    const float* c2a = (const float*)d_in[10];
    const float* g2y = (const float*)d_in[11];

    float* allday = (float*)d_out;
    float* Ccell  = allday + (size_t)B_ * T_ * 7;
    float* Cconv  = Ccell + (size_t)B_ * NS_ * CD_;

    hipLaunchKernelGGL(mclstm_phase1, dim3(B_), dim3(64), 0, stream,
                       X, ORY, Wr, br, Wp, bp, Wc, bc, Wa, ba, Ccell);
    hipLaunchKernelGGL(mclstm_phase2, dim3(NTASK / 256), dim3(256), 0, stream,
                       X, ORY, Wr, br, c2a, g2y, Ccell, allday, Cconv);
}